// Round 10
// baseline (302.789 us; speedup 1.0000x reference)
//
#include <hip/hip_runtime.h>
#include <hip/hip_bf16.h>
#include <cstddef>

#define B_   4
#define S_   1500
#define D_   1280
#define H_   20
#define HD_  64
#define M_   (B_*S_)
#define SPAD 1536
#define BIGNEG (-1e30f)
#define LOG2E 1.44269504088896340736f
#define KVB  64
#define NTA  24   // ceil(1500/64)

typedef short bf16x8 __attribute__((ext_vector_type(8)));
typedef float f32x4 __attribute__((ext_vector_type(4)));
typedef unsigned short u16;
typedef u16 u16x8 __attribute__((ext_vector_type(8)));
typedef unsigned int u32x4v __attribute__((ext_vector_type(4)));

#define MFMA __builtin_amdgcn_mfma_f32_16x16x32_bf16

__device__ __forceinline__ u16 f2bf(float f) {
  union { float f; unsigned u; } x; x.f = f;
  unsigned r = (x.u + 0x7fffu + ((x.u >> 16) & 1u)) >> 16;
  return (u16)r;
}

__device__ __forceinline__ unsigned cvtpk(float a, float b) {
  unsigned r;
  asm volatile("v_cvt_pk_bf16_f32 %0, %1, %2" : "=v"(r) : "v"(a), "v"(b));
  return r;
}

__device__ __forceinline__ void gl_lds16(const u16* g, u16* l) {
  typedef __attribute__((address_space(1))) const unsigned GU;
  typedef __attribute__((address_space(3))) unsigned LU;
  __builtin_amdgcn_global_load_lds((GU*)g, (LU*)l, 16, 0, 0);
}

// ---- fp32 -> bf16 bulk convert (8 elems/thread) ----
__global__ __launch_bounds__(256) void k_conv(const float* __restrict__ X, u16* __restrict__ Y) {
  size_t i = (size_t)blockIdx.x * 256 + threadIdx.x;
  const float4* p = (const float4*)(X + i * 8);
  float4 a = p[0], b = p[1];
  u16x8 v;
  v[0]=f2bf(a.x); v[1]=f2bf(a.y); v[2]=f2bf(a.z); v[3]=f2bf(a.w);
  v[4]=f2bf(b.x); v[5]=f2bf(b.y); v[6]=f2bf(b.z); v[7]=f2bf(b.w);
  *(u16x8*)(Y + i * 8) = v;
}

// ---- 4 weights W[k][n] fp32 -> Wt[n][k] bf16 transpose, z-selected ----
__global__ __launch_bounds__(256) void k_trans4(const float* __restrict__ qw,
                                                const float* __restrict__ kw,
                                                const float* __restrict__ vw,
                                                const float* __restrict__ ow,
                                                u16* __restrict__ Wt) {
  const float* W = (blockIdx.z == 0) ? qw : (blockIdx.z == 1) ? kw
                   : (blockIdx.z == 2) ? vw : ow;
  u16* dst = Wt + (size_t)blockIdx.z * D_ * D_;
  __shared__ float t[32][33];
  int n0 = blockIdx.x * 32, k0 = blockIdx.y * 32;
  int tx = threadIdx.x & 31, ty = threadIdx.x >> 5;
  #pragma unroll
  for (int i = ty; i < 32; i += 8) t[i][tx] = W[(size_t)(k0 + i) * D_ + n0 + tx];
  __syncthreads();
  #pragma unroll
  for (int i = ty; i < 32; i += 8) dst[(size_t)(n0 + i) * D_ + k0 + tx] = f2bf(t[tx][i]);
}

// ---- Vb[M][D] bf16 -> Vt[bh][d][SPAD] bf16, 64-key blocks in PV slot order ----
// slot(k) = ((k>>2)&3)*16 + ((k>>4)&3)*4 + (k&3)  (within each 64-key block)
__global__ __launch_bounds__(256) void k_vtrans(const u16* __restrict__ Vb, u16* __restrict__ Vt) {
  __shared__ u16 t[128][72];
  int bh = blockIdx.x, b = bh / H_, h = bh % H_;
  int s0 = blockIdx.y * 128;
  int tid = threadIdx.x;
  #pragma unroll
  for (int r = 0; r < 4; r++) {
    int sl = r * 32 + (tid >> 3);
    int s = s0 + sl; if (s > S_ - 1) s = S_ - 1;
    bf16x8 v = *(const bf16x8*)(Vb + ((size_t)(b * S_ + s)) * D_ + h * HD_ + (tid & 7) * 8);
    *(bf16x8*)&t[sl][(tid & 7) * 8] = v;
  }
  __syncthreads();
  #pragma unroll
  for (int r = 0; r < 4; r++) {
    int d = r * 16 + (tid >> 4);
    int ss = (tid & 15) * 8;   // slot base 0..120
    u16x8 o;
    #pragma unroll
    for (int q = 0; q < 8; q++) {
      int sl = ss + q;
      int kk = ((sl >> 4) & 3) * 4 + (sl & 3) + ((sl >> 2) & 3) * 16 + (sl & 64);
      o[q] = t[kk][d];
    }
    *(u16x8*)(Vt + ((size_t)bh * HD_ + d) * SPAD + s0 + ss) = o;
  }
}

// ---- Fused QKV GEMM: [M,1280]@[1280,3840] ; 128x128 tile, BK=64, sw-pipelined ----
__global__ __launch_bounds__(256) void k_gemmqkv(const u16* __restrict__ A,
                                                 const u16* __restrict__ Wt,
                                                 const float* __restrict__ q_b,
                                                 const float* __restrict__ v_b,
                                                 u16* __restrict__ Qb) {
  __shared__ u16 As[128 * 64];
  __shared__ u16 Bs[128 * 64];
  int tid = threadIdx.x;
  int lane = tid & 63;
  int wv = tid >> 6;
  int l16 = lane & 15, lg = lane >> 4;
  int wr = wv >> 1, wc = wv & 1;
  int m0 = blockIdx.x * 128;
  int n0g = blockIdx.y * 128;
  int sel = blockIdx.y / 10;                  // 0=Q,1=K,2=V
  int nloc = n0g - sel * 1280;

  int srow = tid >> 3, scol = tid & 7;
  int wcol8 = ((scol ^ (srow & 7))) * 8;

  f32x4 acc[4][4] = {};
  bf16x8 ta[4], tb[4];

#define LOADT(tt) do {                                                    \
    int kk0 = (tt) * 64;                                                  \
    _Pragma("unroll")                                                     \
    for (int c = 0; c < 4; c++) {                                         \
      int row = srow + c * 32;                                            \
      int ar = m0 + row; if (ar > M_ - 1) ar = M_ - 1;                    \
      ta[c] = *(const bf16x8*)(A  + (size_t)ar * D_ + kk0 + scol * 8);    \
      tb[c] = *(const bf16x8*)(Wt + (size_t)(n0g + row) * D_ + kk0 + scol * 8); \
    }                                                                     \
  } while (0)

  LOADT(0);
  for (int t = 0; t < 20; t++) {
    __syncthreads();
    #pragma unroll
    for (int c = 0; c < 4; c++) {
      int row = srow + c * 32;
      *(bf16x8*)&As[row * 64 + wcol8] = ta[c];
      *(bf16x8*)&Bs[row * 64 + wcol8] = tb[c];
    }
    if (t < 19) LOADT(t + 1);
    __syncthreads();
    #pragma unroll
    for (int kk = 0; kk < 2; kk++) {
      int pcol = ((kk * 4 + lg) ^ (l16 & 7)) * 8;
      bf16x8 af[4], bf[4];
      #pragma unroll
      for (int m = 0; m < 4; m++)
        af[m] = *(const bf16x8*)&As[(wr * 64 + m * 16 + l16) * 64 + pcol];
      #pragma unroll
      for (int n = 0; n < 4; n++)
        bf[n] = *(const bf16x8*)&Bs[(wc * 64 + n * 16 + l16) * 64 + pcol];
      __builtin_amdgcn_s_setprio(1);
      #pragma unroll
      for (int m = 0; m < 4; m++)
        #pragma unroll
        for (int n = 0; n < 4; n++)
          acc[m][n] = MFMA(af[m], bf[n], acc[m][n], 0, 0, 0);
      __builtin_amdgcn_s_setprio(0);
    }
  }
#undef LOADT

  const float* bias = (sel == 0) ? q_b : v_b;
  float scl = (sel == 0) ? (0.125f * LOG2E) : 1.0f;
  u16* outb = Qb + (size_t)sel * ((size_t)M_ * D_);

  #pragma unroll
  for (int m = 0; m < 4; m++) {
    int row0 = m0 + wr * 64 + m * 16 + lg * 4;
    #pragma unroll
    for (int n = 0; n < 4; n++) {
      int colL = nloc + wc * 64 + n * 16 + l16;
      float bv = (sel == 1) ? 0.0f : bias[colL];
      #pragma unroll
      for (int j = 0; j < 4; j++) {
        int row = row0 + j;
        if (row < M_) {
          float v = (acc[m][n][j] + bv) * scl;
          outb[(size_t)row * D_ + colL] = f2bf(v);
        }
      }
    }
  }
}

// ---- O GEMM: out[M,1280] fp32 = Ctx @ Wto + o_b ----
__global__ __launch_bounds__(256) void k_gemmo(const u16* __restrict__ A,
                                               const u16* __restrict__ Wt,
                                               const float* __restrict__ bias,
                                               float* __restrict__ outp) {
  __shared__ u16 As[128 * 64];
  __shared__ u16 Bs[128 * 64];
  int tid = threadIdx.x;
  int lane = tid & 63;
  int wv = tid >> 6;
  int l16 = lane & 15, lg = lane >> 4;
  int wr = wv >> 1, wc = wv & 1;
  int m0 = blockIdx.x * 128, n0 = blockIdx.y * 128;

  int srow = tid >> 3, scol = tid & 7;
  int wcol8 = ((scol ^ (srow & 7))) * 8;

  f32x4 acc[4][4] = {};
  bf16x8 ta[4], tb[4];

#define LOADT(tt) do {                                                    \
    int kk0 = (tt) * 64;                                                  \
    _Pragma("unroll")                                                     \
    for (int c = 0; c < 4; c++) {                                         \
      int row = srow + c * 32;                                            \
      int ar = m0 + row; if (ar > M_ - 1) ar = M_ - 1;                    \
      ta[c] = *(const bf16x8*)(A  + (size_t)ar * D_ + kk0 + scol * 8);    \
      tb[c] = *(const bf16x8*)(Wt + (size_t)(n0 + row) * D_ + kk0 + scol * 8); \
    }                                                                     \
  } while (0)

  LOADT(0);
  for (int t = 0; t < 20; t++) {
    __syncthreads();
    #pragma unroll
    for (int c = 0; c < 4; c++) {
      int row = srow + c * 32;
      *(bf16x8*)&As[row * 64 + wcol8] = ta[c];
      *(bf16x8*)&Bs[row * 64 + wcol8] = tb[c];
    }
    if (t < 19) LOADT(t + 1);
    __syncthreads();
    #pragma unroll
    for (int kk = 0; kk < 2; kk++) {
      int pcol = ((kk * 4 + lg) ^ (l16 & 7)) * 8;
      bf16x8 af[4], bf[4];
      #pragma unroll
      for (int m = 0; m < 4; m++)
        af[m] = *(const bf16x8*)&As[(wr * 64 + m * 16 + l16) * 64 + pcol];
      #pragma unroll
      for (int n = 0; n < 4; n++)
        bf[n] = *(const bf16x8*)&Bs[(wc * 64 + n * 16 + l16) * 64 + pcol];
      __builtin_amdgcn_s_setprio(1);
      #pragma unroll
      for (int m = 0; m < 4; m++)
        #pragma unroll
        for (int n = 0; n < 4; n++)
          acc[m][n] = MFMA(af[m], bf[n], acc[m][n], 0, 0, 0);
      __builtin_amdgcn_s_setprio(0);
    }
  }
#undef LOADT

  #pragma unroll
  for (int m = 0; m < 4; m++) {
    int row0 = m0 + wr * 64 + m * 16 + lg * 4;
    #pragma unroll
    for (int n = 0; n < 4; n++) {
      int col = n0 + wc * 64 + n * 16 + l16;
      float bv = bias[col];
      #pragma unroll
      for (int j = 0; j < 4; j++) {
        int row = row0 + j;
        if (row < M_) outp[(size_t)row * D_ + col] = acc[m][n][j] + bv;
      }
    }
  }
}

// ---- Flash attention: 8 waves/block, 128 q-rows, KVB=64, LDS K/V dbuf ----
// grid (12, 80), 512 threads; LDS 32KB shared by 8 waves.
// Plain launch_bounds: ANY min-waves hint forced spills (r8: 32 VGPR/spill,
// r9: 44 VGPR/spill). Natural allocation ~64-72 VGPR, no scratch.
__global__ __launch_bounds__(512) void k_attn(const u16* __restrict__ Qb,
                                              const u16* __restrict__ Kb,
                                              const u16* __restrict__ Vt,
                                              const float* __restrict__ mask,
                                              u16* __restrict__ Ctx) {
  __shared__ u16 Kl[2][64 * 64];   // [key][d]        128B rows, 16B-chunk XOR (row&7)
  __shared__ u16 Vl[2][64 * 64];   // [d][key-slot]   128B rows, 16B-chunk XOR (row&7)

  int tid = threadIdx.x;
  int lane = tid & 63, wv = tid >> 6;       // 8 waves
  int l16 = lane & 15, lg = lane >> 4;
  int bh = blockIdx.y, b = bh / H_, h = bh % H_;
  int qw0 = blockIdx.x * 128 + wv * 16;

  int qr = qw0 + l16; if (qr > S_ - 1) qr = S_ - 1;
  const u16* qp = Qb + ((size_t)(b * S_ + qr)) * D_ + h * HD_ + lg * 8;
  bf16x8 aq0 = *(const bf16x8*)(qp);
  bf16x8 aq1 = *(const bf16x8*)(qp + 32);
  const float* mrow = mask + (size_t)b * S_ * S_ + (size_t)qr * S_;

  // staging: each thread stages one 16B chunk of K and one of V per tile.
  // wave wv owns rows wv*8..wv*8+7 ; LDS base = wv*512 u16 (8 rows x 64 u16).
  int srw = lane >> 3;                        // dest row & 7
  int csw = ((lane & 7) ^ srw) * 8;           // inverse-swizzled source elem offset
  int kdrow = wv * 8 + srw;                   // key row (K) / d row (V)
  const u16* ksrc = Kb + (size_t)b * S_ * D_ + h * HD_ + csw;          // + key*D_
  const u16* vsrc = Vt + ((size_t)bh * HD_ + kdrow) * SPAD + csw;      // + k0

  float m_ = BIGNEG, l_ = 0.0f;
  f32x4 acc[4] = {};
  const f32x4 zf = {0, 0, 0, 0};

#define STAGE(k0s, bufb) do {                                          \
    int key_ = (k0s) + kdrow; if (key_ > S_ - 1) key_ = S_ - 1;        \
    gl_lds16(ksrc + (size_t)key_ * D_, &Kl[bufb][0] + wv * 512);       \
    gl_lds16(vsrc + (k0s),             &Vl[bufb][0] + wv * 512);       \
  } while (0)

#define COMPUTE(curb, k0_, LASTV) do {                                 \
    const u16* KlC = &Kl[curb][0];                                     \
    const u16* VlC = &Vl[curb][0];                                     \
    f32x4 s[4];                                                        \
    __builtin_amdgcn_s_setprio(1);                                     \
    _Pragma("unroll")                                                  \
    for (int sub = 0; sub < 4; sub++) {                                \
      const u16* kb = KlC + (sub * 16 + l16) * 64;                     \
      bf16x8 kf0 = *(const bf16x8*)(kb + ((lg     ^ (l16 & 7)) * 8));  \
      bf16x8 kf1 = *(const bf16x8*)(kb + (((4+lg) ^ (l16 & 7)) * 8));  \
      s[sub] = MFMA(kf0, aq0, zf, 0, 0, 0);                            \
      s[sub] = MFMA(kf1, aq1, s[sub], 0, 0, 0);                        \
    }                                                                  \
    __builtin_amdgcn_s_setprio(0);                                     \
    _Pragma("unroll")                                                  \
    for (int sub = 0; sub < 4; sub++) {                                \
      float4 mv;                                                       \
      if (!(LASTV)) {                                                  \
        mv = *(const float4*)(mrow + (k0_) + sub * 16 + lg * 4);       \
      } else {                                                         \
        int mc = (k0_) + sub * 16 + lg * 4; if (mc > S_ - 4) mc = S_ - 4; \
        mv = *(const float4*)(mrow + mc);                              \
      }                                                                \
      s[sub][0] = fmaf(mv.x, LOG2E, s[sub][0]);                        \
      s[sub][1] = fmaf(mv.y, LOG2E, s[sub][1]);                        \
      s[sub][2] = fmaf(mv.z, LOG2E, s[sub][2]);                        \
      s[sub][3] = fmaf(mv.w, LOG2E, s[sub][3]);                        \
    }                                                                  \
    if (LASTV) {                                                       \
      _Pragma("unroll")                                                \
      for (int sub = 0; sub < 4; sub++) {                              \
        int kb_ = (k0_) + sub * 16 + lg * 4;                           \
        _Pragma("unroll")                                              \
        for (int j = 0; j < 4; j++)                                    \
          if (kb_ + j >= S_) s[sub][j] = BIGNEG;                       \
      }                                                                \
    }                                                                  \
    float t0 = fmaxf(fmaxf(s[0][0], s[0][1]), fmaxf(s[0][2], s[0][3]));\
    float t1 = fmaxf(fmaxf(s[1][0], s[1][1]), fmaxf(s[1][2], s[1][3]));\
    float t2 = fmaxf(fmaxf(s[2][0], s[2][1]), fmaxf(s[2][2], s[2][3]));\
    float t3 = fmaxf(fmaxf(s[3][0], s[3][1]), fmaxf(s[3][2], s[3][3]));\
    float rmax = fmaxf(fmaxf(t0, t1), fmaxf(t2, t3));                  \
    rmax = fmaxf(rmax, __shfl_xor(rmax, 16));                          \
    rmax = fmaxf(rmax, __shfl_xor(rmax, 32));                          \
    float mn = fmaxf(m_, rmax);                                        \
    if (!__all(mn - m_ <= 8.0f)) {                                     \
      float c = __builtin_amdgcn_exp2f(m_ - mn);                       \
      m_ = mn; l_ *= c;                                                \
      _Pragma("unroll")                                                \
      for (int j = 0; j < 4; j++) {                                    \
        float cj = __shfl(c, lg * 4 + j);                              \
        acc[0][j] *= cj; acc[1][j] *= cj;                              \
        acc[2][j] *= cj; acc[3][j] *= cj;                              \
      }                                                                \
    }                                                                  \
    _Pragma("unroll")                                                  \
    for (int sub = 0; sub < 4; sub++)                                  \
      _Pragma("unroll")                                                \
      for (int j = 0; j < 4; j++)                                      \
        s[sub][j] = __builtin_amdgcn_exp2f(s[sub][j] - m_);            \
    float a0 = (s[0][0] + s[0][1]) + (s[0][2] + s[0][3]);              \
    float a1 = (s[1][0] + s[1][1]) + (s[1][2] + s[1][3]);              \
    float a2 = (s[2][0] + s[2][1]) + (s[2][2] + s[2][3]);              \
    float a3 = (s[3][0] + s[3][1]) + (s[3][2] + s[3][3]);              \
    float rs = (a0 + a1) + (a2 + a3);                                  \
    rs += __shfl_xor(rs, 16);                                          \
    rs += __shfl_xor(rs, 32);                                          \
    l_ += rs;                                                          \
    /* PV half 0: keys k0..k0+31 (subs 0,1) */                         \
    {                                                                  \
      union { u32x4v u; bf16x8 bf; } pc;                               \
      pc.u[0] = cvtpk(s[0][0], s[0][1]); pc.u[1] = cvtpk(s[0][2], s[0][3]); \
      pc.u[2] = cvtpk(s[1][0], s[1][1]); pc.u[3] = cvtpk(s[1][2], s[1][3]); \
      __builtin_amdgcn_s_setprio(1);                                   \
      _Pragma("unroll")                                                \
      for (int n = 0; n < 4; n++) {                                    \
        const u16* vb = VlC + (n * 16 + l16) * 64;                     \
        bf16x8 bv = *(const bf16x8*)(vb + (((lg*2  ) ^ (l16 & 7)) * 8)); \
        acc[n] = MFMA(pc.bf, bv, acc[n], 0, 0, 0);                     \
      }                                                                \
      __builtin_amdgcn_s_setprio(0);                                   \
    }                                                                  \
    /* PV half 1: keys k0+32..k0+63 (subs 2,3) */                      \
    {                                                                  \
      union { u32x4v u; bf16x8 bf; } pc;                               \
      pc.u[0] = cvtpk(s[2][0], s[2][1]); pc.u[1] = cvtpk(s[2][2], s[2][3]); \
      pc.u[2] = cvtpk(s[3][0], s[3][1]); pc.u[3] = cvtpk(s[3][2], s[3][3]); \
      __builtin_amdgcn_s_setprio(1);                                   \
      _Pragma("unroll")                                                \
      for (int n = 0; n < 4; n++) {                                    \
        const u16* vb = VlC + (n * 16 + l16) * 64;                     \
        bf16x8 bv = *(const bf16x8*)(vb + (((lg*2+1) ^ (l16 & 7)) * 8)); \
        acc[n] = MFMA(pc.bf, bv, acc[n], 0, 0, 0);                     \
      }                                                                \
      __builtin_amdgcn_s_setprio(0);                                   \
    }                                                                  \
  } while (0)

  STAGE(0, 0);

  for (int t = 0; t < NTA - 1; t++) {
    int k0 = t * KVB;
    __builtin_amdgcn_s_barrier();
    asm volatile("" ::: "memory");
    STAGE(k0 + KVB, (t + 1) & 1);
    asm volatile("s_waitcnt vmcnt(2)" ::: "memory");
    __builtin_amdgcn_s_barrier();
    asm volatile("" ::: "memory");
    COMPUTE(t & 1, k0, false);
  }
  {
    const int k0 = (NTA - 1) * KVB;   // 1472, tail = 28 keys
    __builtin_amdgcn_s_barrier();
    asm volatile("s_waitcnt vmcnt(0)" ::: "memory");
    __builtin_amdgcn_s_barrier();
    asm volatile("" ::: "memory");
    COMPUTE((NTA - 1) & 1, k0, true);
  }

  float inv = 1.0f / l_;
  #pragma unroll
  for (int j = 0; j < 4; j++) {
    float invj = __shfl(inv, lg * 4 + j);
    int row = qw0 + lg * 4 + j;
    if (row < S_) {
      #pragma unroll
      for (int n = 0; n < 4; n++) {
        float v = acc[n][j] * invj;
        Ctx[((size_t)(b * S_ + row)) * D_ + h * HD_ + n * 16 + l16] = f2bf(v);
      }
    }
  }
#undef STAGE
#undef COMPUTE
}

extern "C" void kernel_launch(void* const* d_in, const int* in_sizes, int n_in,
                              void* d_out, int out_size, void* d_ws, size_t ws_size,
                              hipStream_t stream) {
  const float* hs   = (const float*)d_in[0];
  const float* mask = (const float*)d_in[1];
  const float* q_w  = (const float*)d_in[2];
  const float* q_b  = (const float*)d_in[3];
  const float* k_w  = (const float*)d_in[4];
  const float* v_w  = (const float*)d_in[5];
  const float* v_b  = (const float*)d_in[6];
  const float* o_w  = (const float*)d_in[7];
  const float* o_b  = (const float*)d_in[8];
  float* out = (float*)d_out;

  char* w = (char*)d_ws;
  const size_t XD = (size_t)M_ * D_;
  const size_t WD = (size_t)D_ * D_;
  u16* Xb  = (u16*)(w);                 w += XD * 2;
  u16* Wtq = (u16*)(w);                 w += WD * 2;   // q,k,v,o contiguous
  u16* Wtk = (u16*)(w);                 w += WD * 2;
  u16* Wtv = (u16*)(w);                 w += WD * 2;
  u16* Wto = (u16*)(w);                 w += WD * 2;
  u16* Qb  = (u16*)(w);                 w += XD * 2;   // q,k,v outputs contiguous
  u16* Kb  = (u16*)(w);                 w += XD * 2;
  u16* Vb  = (u16*)(w);                 w += XD * 2;
  u16* Vt  = (u16*)(w);                 w += (size_t)B_ * H_ * HD_ * SPAD * 2;
  u16* Ctx = Xb;   // alias: Xb dead after QKV projection
  (void)Wtk; (void)Wtv;

  k_conv<<<dim3(3750), dim3(256), 0, stream>>>(hs, Xb);
  k_trans4<<<dim3(40, 40, 4), dim3(256), 0, stream>>>(q_w, k_w, v_w, o_w, Wtq);

  k_gemmqkv<<<dim3(47, 30), dim3(256), 0, stream>>>(Xb, Wtq, q_b, v_b, Qb);
  k_vtrans<<<dim3(80, 12), dim3(256), 0, stream>>>(Vb, Vt);

  k_attn<<<dim3(12, 80), dim3(512), 0, stream>>>(Qb, Kb, Vt, mask, Ctx);

  k_gemmo<<<dim3(47, 10), dim3(256), 0, stream>>>(Ctx, Wto, o_b, out);
}

// Round 11
// 280.383 us; speedup vs baseline: 1.0799x; 1.0799x over previous
//
#include <hip/hip_runtime.h>
#include <hip/hip_bf16.h>
#include <cstddef>

#define B_   4
#define S_   1500
#define D_   1280
#define H_   20
#define HD_  64
#define M_   (B_*S_)
#define SPAD 1536
#define BIGNEG (-1e30f)
#define LOG2E 1.44269504088896340736f
#define KVB  64
#define NTA  24   // ceil(1500/64)

typedef short bf16x8 __attribute__((ext_vector_type(8)));
typedef float f32x4 __attribute__((ext_vector_type(4)));
typedef unsigned short u16;
typedef u16 u16x8 __attribute__((ext_vector_type(8)));
typedef unsigned int u32x4v __attribute__((ext_vector_type(4)));

#define MFMA __builtin_amdgcn_mfma_f32_16x16x32_bf16

__device__ __forceinline__ u16 f2bf(float f) {
  union { float f; unsigned u; } x; x.f = f;
  unsigned r = (x.u + 0x7fffu + ((x.u >> 16) & 1u)) >> 16;
  return (u16)r;
}

__device__ __forceinline__ unsigned cvtpk(float a, float b) {
  unsigned r;
  asm volatile("v_cvt_pk_bf16_f32 %0, %1, %2" : "=v"(r) : "v"(a), "v"(b));
  return r;
}

__device__ __forceinline__ void gl_lds16(const u16* g, u16* l) {
  typedef __attribute__((address_space(1))) const unsigned GU;
  typedef __attribute__((address_space(3))) unsigned LU;
  __builtin_amdgcn_global_load_lds((GU*)g, (LU*)l, 16, 0, 0);
}

// ---- fp32 -> bf16 bulk convert (8 elems/thread) ----
__global__ __launch_bounds__(256) void k_conv(const float* __restrict__ X, u16* __restrict__ Y) {
  size_t i = (size_t)blockIdx.x * 256 + threadIdx.x;
  const float4* p = (const float4*)(X + i * 8);
  float4 a = p[0], b = p[1];
  u16x8 v;
  v[0]=f2bf(a.x); v[1]=f2bf(a.y); v[2]=f2bf(a.z); v[3]=f2bf(a.w);
  v[4]=f2bf(b.x); v[5]=f2bf(b.y); v[6]=f2bf(b.z); v[7]=f2bf(b.w);
  *(u16x8*)(Y + i * 8) = v;
}

// ---- 4 weights W[k][n] fp32 -> Wt[n][k] bf16 transpose, z-selected ----
__global__ __launch_bounds__(256) void k_trans4(const float* __restrict__ qw,
                                                const float* __restrict__ kw,
                                                const float* __restrict__ vw,
                                                const float* __restrict__ ow,
                                                u16* __restrict__ Wt) {
  const float* W = (blockIdx.z == 0) ? qw : (blockIdx.z == 1) ? kw
                   : (blockIdx.z == 2) ? vw : ow;
  u16* dst = Wt + (size_t)blockIdx.z * D_ * D_;
  __shared__ float t[32][33];
  int n0 = blockIdx.x * 32, k0 = blockIdx.y * 32;
  int tx = threadIdx.x & 31, ty = threadIdx.x >> 5;
  #pragma unroll
  for (int i = ty; i < 32; i += 8) t[i][tx] = W[(size_t)(k0 + i) * D_ + n0 + tx];
  __syncthreads();
  #pragma unroll
  for (int i = ty; i < 32; i += 8) dst[(size_t)(n0 + i) * D_ + k0 + tx] = f2bf(t[tx][i]);
}

// ---- Vb[M][D] bf16 -> Vt[bh][d][SPAD] bf16, 64-key blocks in PV slot order ----
// slot(k) = ((k>>2)&3)*16 + ((k>>4)&3)*4 + (k&3)  (within each 64-key block)
__global__ __launch_bounds__(256) void k_vtrans(const u16* __restrict__ Vb, u16* __restrict__ Vt) {
  __shared__ u16 t[128][72];
  int bh = blockIdx.x, b = bh / H_, h = bh % H_;
  int s0 = blockIdx.y * 128;
  int tid = threadIdx.x;
  #pragma unroll
  for (int r = 0; r < 4; r++) {
    int sl = r * 32 + (tid >> 3);
    int s = s0 + sl; if (s > S_ - 1) s = S_ - 1;
    bf16x8 v = *(const bf16x8*)(Vb + ((size_t)(b * S_ + s)) * D_ + h * HD_ + (tid & 7) * 8);
    *(bf16x8*)&t[sl][(tid & 7) * 8] = v;
  }
  __syncthreads();
  #pragma unroll
  for (int r = 0; r < 4; r++) {
    int d = r * 16 + (tid >> 4);
    int ss = (tid & 15) * 8;   // slot base 0..120
    u16x8 o;
    #pragma unroll
    for (int q = 0; q < 8; q++) {
      int sl = ss + q;
      int kk = ((sl >> 4) & 3) * 4 + (sl & 3) + ((sl >> 2) & 3) * 16 + (sl & 64);
      o[q] = t[kk][d];
    }
    *(u16x8*)(Vt + ((size_t)bh * HD_ + d) * SPAD + s0 + ss) = o;
  }
}

// ---- Fused QKV GEMM: [M,1280]@[1280,3840] ; 128x128 tile, BK=64, sw-pipelined ----
__global__ __launch_bounds__(256) void k_gemmqkv(const u16* __restrict__ A,
                                                 const u16* __restrict__ Wt,
                                                 const float* __restrict__ q_b,
                                                 const float* __restrict__ v_b,
                                                 u16* __restrict__ Qb) {
  __shared__ u16 As[128 * 64];
  __shared__ u16 Bs[128 * 64];
  int tid = threadIdx.x;
  int lane = tid & 63;
  int wv = tid >> 6;
  int l16 = lane & 15, lg = lane >> 4;
  int wr = wv >> 1, wc = wv & 1;
  int m0 = blockIdx.x * 128;
  int n0g = blockIdx.y * 128;
  int sel = blockIdx.y / 10;                  // 0=Q,1=K,2=V
  int nloc = n0g - sel * 1280;

  int srow = tid >> 3, scol = tid & 7;
  int wcol8 = ((scol ^ (srow & 7))) * 8;

  f32x4 acc[4][4] = {};
  bf16x8 ta[4], tb[4];

#define LOADT(tt) do {                                                    \
    int kk0 = (tt) * 64;                                                  \
    _Pragma("unroll")                                                     \
    for (int c = 0; c < 4; c++) {                                         \
      int row = srow + c * 32;                                            \
      int ar = m0 + row; if (ar > M_ - 1) ar = M_ - 1;                    \
      ta[c] = *(const bf16x8*)(A  + (size_t)ar * D_ + kk0 + scol * 8);    \
      tb[c] = *(const bf16x8*)(Wt + (size_t)(n0g + row) * D_ + kk0 + scol * 8); \
    }                                                                     \
  } while (0)

  LOADT(0);
  for (int t = 0; t < 20; t++) {
    __syncthreads();
    #pragma unroll
    for (int c = 0; c < 4; c++) {
      int row = srow + c * 32;
      *(bf16x8*)&As[row * 64 + wcol8] = ta[c];
      *(bf16x8*)&Bs[row * 64 + wcol8] = tb[c];
    }
    if (t < 19) LOADT(t + 1);
    __syncthreads();
    #pragma unroll
    for (int kk = 0; kk < 2; kk++) {
      int pcol = ((kk * 4 + lg) ^ (l16 & 7)) * 8;
      bf16x8 af[4], bf[4];
      #pragma unroll
      for (int m = 0; m < 4; m++)
        af[m] = *(const bf16x8*)&As[(wr * 64 + m * 16 + l16) * 64 + pcol];
      #pragma unroll
      for (int n = 0; n < 4; n++)
        bf[n] = *(const bf16x8*)&Bs[(wc * 64 + n * 16 + l16) * 64 + pcol];
      __builtin_amdgcn_s_setprio(1);
      #pragma unroll
      for (int m = 0; m < 4; m++)
        #pragma unroll
        for (int n = 0; n < 4; n++)
          acc[m][n] = MFMA(af[m], bf[n], acc[m][n], 0, 0, 0);
      __builtin_amdgcn_s_setprio(0);
    }
  }
#undef LOADT

  const float* bias = (sel == 0) ? q_b : v_b;
  float scl = (sel == 0) ? (0.125f * LOG2E) : 1.0f;
  u16* outb = Qb + (size_t)sel * ((size_t)M_ * D_);

  #pragma unroll
  for (int m = 0; m < 4; m++) {
    int row0 = m0 + wr * 64 + m * 16 + lg * 4;
    #pragma unroll
    for (int n = 0; n < 4; n++) {
      int colL = nloc + wc * 64 + n * 16 + l16;
      float bv = (sel == 1) ? 0.0f : bias[colL];
      #pragma unroll
      for (int j = 0; j < 4; j++) {
        int row = row0 + j;
        if (row < M_) {
          float v = (acc[m][n][j] + bv) * scl;
          outb[(size_t)row * D_ + colL] = f2bf(v);
        }
      }
    }
  }
}

// ---- O GEMM: out[M,1280] fp32 = Ctx @ Wto + o_b ----
__global__ __launch_bounds__(256) void k_gemmo(const u16* __restrict__ A,
                                               const u16* __restrict__ Wt,
                                               const float* __restrict__ bias,
                                               float* __restrict__ outp) {
  __shared__ u16 As[128 * 64];
  __shared__ u16 Bs[128 * 64];
  int tid = threadIdx.x;
  int lane = tid & 63;
  int wv = tid >> 6;
  int l16 = lane & 15, lg = lane >> 4;
  int wr = wv >> 1, wc = wv & 1;
  int m0 = blockIdx.x * 128, n0 = blockIdx.y * 128;

  int srow = tid >> 3, scol = tid & 7;
  int wcol8 = ((scol ^ (srow & 7))) * 8;

  f32x4 acc[4][4] = {};
  bf16x8 ta[4], tb[4];

#define LOADT(tt) do {                                                    \
    int kk0 = (tt) * 64;                                                  \
    _Pragma("unroll")                                                     \
    for (int c = 0; c < 4; c++) {                                         \
      int row = srow + c * 32;                                            \
      int ar = m0 + row; if (ar > M_ - 1) ar = M_ - 1;                    \
      ta[c] = *(const bf16x8*)(A  + (size_t)ar * D_ + kk0 + scol * 8);    \
      tb[c] = *(const bf16x8*)(Wt + (size_t)(n0 + row) * D_ + kk0 + scol * 8); \
    }                                                                     \
  } while (0)

  LOADT(0);
  for (int t = 0; t < 20; t++) {
    __syncthreads();
    #pragma unroll
    for (int c = 0; c < 4; c++) {
      int row = srow + c * 32;
      *(bf16x8*)&As[row * 64 + wcol8] = ta[c];
      *(bf16x8*)&Bs[row * 64 + wcol8] = tb[c];
    }
    if (t < 19) LOADT(t + 1);
    __syncthreads();
    #pragma unroll
    for (int kk = 0; kk < 2; kk++) {
      int pcol = ((kk * 4 + lg) ^ (l16 & 7)) * 8;
      bf16x8 af[4], bf[4];
      #pragma unroll
      for (int m = 0; m < 4; m++)
        af[m] = *(const bf16x8*)&As[(wr * 64 + m * 16 + l16) * 64 + pcol];
      #pragma unroll
      for (int n = 0; n < 4; n++)
        bf[n] = *(const bf16x8*)&Bs[(wc * 64 + n * 16 + l16) * 64 + pcol];
      __builtin_amdgcn_s_setprio(1);
      #pragma unroll
      for (int m = 0; m < 4; m++)
        #pragma unroll
        for (int n = 0; n < 4; n++)
          acc[m][n] = MFMA(af[m], bf[n], acc[m][n], 0, 0, 0);
      __builtin_amdgcn_s_setprio(0);
    }
  }
#undef LOADT

  #pragma unroll
  for (int m = 0; m < 4; m++) {
    int row0 = m0 + wr * 64 + m * 16 + lg * 4;
    #pragma unroll
    for (int n = 0; n < 4; n++) {
      int col = n0 + wc * 64 + n * 16 + l16;
      float bv = bias[col];
      #pragma unroll
      for (int j = 0; j < 4; j++) {
        int row = row0 + j;
        if (row < M_) outp[(size_t)row * D_ + col] = acc[m][n][j] + bv;
      }
    }
  }
}

// ---- Flash attention: r6 structure (4 waves, 256 thr, 64 q-rows) ----
// grid 1920 (1D, XCD-swizzled), KVB=64, LDS K/V dbuf, slot-permuted V b128 PV
__global__ __launch_bounds__(256) void k_attn(const u16* __restrict__ Qb,
                                              const u16* __restrict__ Kb,
                                              const u16* __restrict__ Vt,
                                              const float* __restrict__ mask,
                                              u16* __restrict__ Ctx) {
  __shared__ u16 Kl[2][64 * 64];   // [key][d]        128B rows, 16B-chunk XOR (row&7)
  __shared__ u16 Vl[2][64 * 64];   // [d][key-slot]   128B rows, 16B-chunk XOR (row&7)

  // XCD swizzle: physical p -> logical L so that the 20 heads sharing one
  // (b, q-tile) mask slab are consecutive on ONE XCD. 1920 = 8 * 240.
  int p = blockIdx.x;
  int L = (p & 7) * 240 + (p >> 3);
  int h = L % 20;
  int g = L / 20;            // b*24 + x
  int b = g / 24;
  int xq = g % 24;
  int bh = b * H_ + h;

  int tid = threadIdx.x;
  int lane = tid & 63, wv = tid >> 6;
  int l16 = lane & 15, lg = lane >> 4;
  int qw0 = xq * 64 + wv * 16;

  int qr = qw0 + l16; if (qr > S_ - 1) qr = S_ - 1;
  const u16* qp = Qb + ((size_t)(b * S_ + qr)) * D_ + h * HD_ + lg * 8;
  bf16x8 aq0 = *(const bf16x8*)(qp);
  bf16x8 aq1 = *(const bf16x8*)(qp + 32);
  const float* mrow = mask + (size_t)b * S_ * S_ + (size_t)qr * S_;

  // staging: 4 waves x 2 rows each for K and V (r6 scheme, vmcnt(4))
  int sr0 = wv * 16 + (lane >> 3);
  int csw = ((lane & 7) ^ (lane >> 3)) * 8;  // inverse-swizzled source elem offset
  const u16* ksrc = Kb + (size_t)b * S_ * D_ + h * HD_ + csw;
  const u16* vsrc0 = Vt + ((size_t)bh * HD_ + sr0) * SPAD + csw;
  const u16* vsrc1 = vsrc0 + 8 * SPAD;

  float m_ = BIGNEG, l_ = 0.0f;
  f32x4 acc[4] = {};
  const f32x4 zf = {0, 0, 0, 0};
  float4 mvs[4];

#define STAGE(k0s, bufb) do {                                          \
    int key0_ = (k0s) + sr0;     if (key0_ > S_ - 1) key0_ = S_ - 1;   \
    int key1_ = key0_ + 8;       if (key1_ > S_ - 1) key1_ = S_ - 1;   \
    u16* kd_ = &Kl[bufb][0] + wv * 1024;                               \
    u16* vd_ = &Vl[bufb][0] + wv * 1024;                               \
    gl_lds16(ksrc + (size_t)key0_ * D_, kd_);                          \
    gl_lds16(ksrc + (size_t)key1_ * D_, kd_ + 512);                    \
    gl_lds16(vsrc0 + (k0s), vd_);                                      \
    gl_lds16(vsrc1 + (k0s), vd_ + 512);                                \
  } while (0)

#define COMPUTE(curb, k0_, LASTV) do {                                 \
    const u16* KlC = &Kl[curb][0];                                     \
    const u16* VlC = &Vl[curb][0];                                     \
    f32x4 s[4];                                                        \
    __builtin_amdgcn_s_setprio(1);                                     \
    _Pragma("unroll")                                                  \
    for (int sub = 0; sub < 4; sub++) {                                \
      const u16* kb = KlC + (sub * 16 + l16) * 64;                     \
      bf16x8 kf0 = *(const bf16x8*)(kb + ((lg     ^ (l16 & 7)) * 8));  \
      bf16x8 kf1 = *(const bf16x8*)(kb + (((4+lg) ^ (l16 & 7)) * 8));  \
      s[sub] = MFMA(kf0, aq0, zf, 0, 0, 0);                            \
      s[sub] = MFMA(kf1, aq1, s[sub], 0, 0, 0);                        \
    }                                                                  \
    __builtin_amdgcn_s_setprio(0);                                     \
    _Pragma("unroll")                                                  \
    for (int sub = 0; sub < 4; sub++) {                                \
      s[sub][0] = fmaf(mvs[sub].x, LOG2E, s[sub][0]);                  \
      s[sub][1] = fmaf(mvs[sub].y, LOG2E, s[sub][1]);                  \
      s[sub][2] = fmaf(mvs[sub].z, LOG2E, s[sub][2]);                  \
      s[sub][3] = fmaf(mvs[sub].w, LOG2E, s[sub][3]);                  \
    }                                                                  \
    if (LASTV) {                                                       \
      _Pragma("unroll")                                                \
      for (int sub = 0; sub < 4; sub++) {                              \
        int kb_ = (k0_) + sub * 16 + lg * 4;                           \
        _Pragma("unroll")                                              \
        for (int j = 0; j < 4; j++)                                    \
          if (kb_ + j >= S_) s[sub][j] = BIGNEG;                       \
      }                                                                \
    }                                                                  \
    float t0 = fmaxf(fmaxf(s[0][0], s[0][1]), fmaxf(s[0][2], s[0][3]));\
    float t1 = fmaxf(fmaxf(s[1][0], s[1][1]), fmaxf(s[1][2], s[1][3]));\
    float t2 = fmaxf(fmaxf(s[2][0], s[2][1]), fmaxf(s[2][2], s[2][3]));\
    float t3 = fmaxf(fmaxf(s[3][0], s[3][1]), fmaxf(s[3][2], s[3][3]));\
    float rmax = fmaxf(fmaxf(t0, t1), fmaxf(t2, t3));                  \
    rmax = fmaxf(rmax, __shfl_xor(rmax, 16));                          \
    rmax = fmaxf(rmax, __shfl_xor(rmax, 32));                          \
    float mn = fmaxf(m_, rmax);                                        \
    if (!__all(mn - m_ <= 8.0f)) {                                     \
      float c = __builtin_amdgcn_exp2f(m_ - mn);                       \
      m_ = mn; l_ *= c;                                                \
      _Pragma("unroll")                                                \
      for (int j = 0; j < 4; j++) {                                    \
        float cj = __shfl(c, lg * 4 + j);                              \
        acc[0][j] *= cj; acc[1][j] *= cj;                              \
        acc[2][j] *= cj; acc[3][j] *= cj;                              \
      }                                                                \
    }                                                                  \
    _Pragma("unroll")                                                  \
    for (int sub = 0; sub < 4; sub++)                                  \
      _Pragma("unroll")                                                \
      for (int j = 0; j < 4; j++)                                      \
        s[sub][j] = __builtin_amdgcn_exp2f(s[sub][j] - m_);            \
    float a0 = (s[0][0] + s[0][1]) + (s[0][2] + s[0][3]);              \
    float a1 = (s[1][0] + s[1][1]) + (s[1][2] + s[1][3]);              \
    float a2 = (s[2][0] + s[2][1]) + (s[2][2] + s[2][3]);              \
    float a3 = (s[3][0] + s[3][1]) + (s[3][2] + s[3][3]);              \
    float rs = (a0 + a1) + (a2 + a3);                                  \
    rs += __shfl_xor(rs, 16);                                          \
    rs += __shfl_xor(rs, 32);                                          \
    l_ += rs;                                                          \
    /* PV half 0: subs 0,1 -> slot chunk lg*2 (b128, conflict-free) */ \
    {                                                                  \
      union { u32x4v u; bf16x8 bf; } pc;                               \
      pc.u[0] = cvtpk(s[0][0], s[0][1]); pc.u[1] = cvtpk(s[0][2], s[0][3]); \
      pc.u[2] = cvtpk(s[1][0], s[1][1]); pc.u[3] = cvtpk(s[1][2], s[1][3]); \
      __builtin_amdgcn_s_setprio(1);                                   \
      _Pragma("unroll")                                                \
      for (int n = 0; n < 4; n++) {                                    \
        const u16* vb = VlC + (n * 16 + l16) * 64;                     \
        bf16x8 bv = *(const bf16x8*)(vb + (((lg*2  ) ^ (l16 & 7)) * 8)); \
        acc[n] = MFMA(pc.bf, bv, acc[n], 0, 0, 0);                     \
      }                                                                \
      __builtin_amdgcn_s_setprio(0);                                   \
    }                                                                  \
    /* PV half 1: subs 2,3 -> slot chunk lg*2+1 */                     \
    {                                                                  \
      union { u32x4v u; bf16x8 bf; } pc;                               \
      pc.u[0] = cvtpk(s[2][0], s[2][1]); pc.u[1] = cvtpk(s[2][2], s[2][3]); \
      pc.u[2] = cvtpk(s[3][0], s[3][1]); pc.u[3] = cvtpk(s[3][2], s[3][3]); \
      __builtin_amdgcn_s_setprio(1);                                   \
      _Pragma("unroll")                                                \
      for (int n = 0; n < 4; n++) {                                    \
        const u16* vb = VlC + (n * 16 + l16) * 64;                     \
        bf16x8 bv = *(const bf16x8*)(vb + (((lg*2+1) ^ (l16 & 7)) * 8)); \
        acc[n] = MFMA(pc.bf, bv, acc[n], 0, 0, 0);                     \
      }                                                                \
      __builtin_amdgcn_s_setprio(0);                                   \
    }                                                                  \
  } while (0)

  STAGE(0, 0);

  for (int t = 0; t < NTA - 1; t++) {
    int k0 = t * KVB;
    #pragma unroll
    for (int sub = 0; sub < 4; sub++)
      mvs[sub] = *(const float4*)(mrow + k0 + sub * 16 + lg * 4);
    __builtin_amdgcn_s_barrier();
    asm volatile("" ::: "memory");
    STAGE(k0 + KVB, (t + 1) & 1);
    asm volatile("s_waitcnt vmcnt(4)" ::: "memory");
    __builtin_amdgcn_s_barrier();
    asm volatile("" ::: "memory");
    COMPUTE(t & 1, k0, false);
  }
  {
    const int k0 = (NTA - 1) * KVB;   // 1472, tail = 28 keys
    #pragma unroll
    for (int sub = 0; sub < 4; sub++) {
      int mc = k0 + sub * 16 + lg * 4; if (mc > S_ - 4) mc = S_ - 4;
      mvs[sub] = *(const float4*)(mrow + mc);
    }
    __builtin_amdgcn_s_barrier();
    asm volatile("s_waitcnt vmcnt(0)" ::: "memory");
    __builtin_amdgcn_s_barrier();
    asm volatile("" ::: "memory");
    COMPUTE((NTA - 1) & 1, k0, true);
  }

  float inv = 1.0f / l_;
  #pragma unroll
  for (int j = 0; j < 4; j++) {
    float invj = __shfl(inv, lg * 4 + j);
    int row = qw0 + lg * 4 + j;
    if (row < S_) {
      #pragma unroll
      for (int n = 0; n < 4; n++) {
        float v = acc[n][j] * invj;
        Ctx[((size_t)(b * S_ + row)) * D_ + h * HD_ + n * 16 + l16] = f2bf(v);
      }
    }
  }
#undef STAGE
#undef COMPUTE
}

extern "C" void kernel_launch(void* const* d_in, const int* in_sizes, int n_in,
                              void* d_out, int out_size, void* d_ws, size_t ws_size,
                              hipStream_t stream) {
  const float* hs   = (const float*)d_in[0];
  const float* mask = (const float*)d_in[1];
  const float* q_w  = (const float*)d_in[2];
  const float* q_b  = (const float*)d_in[3];
  const float* k_w  = (const float*)d_in[4];
  const float* v_w  = (const float*)d_in[5];
  const float* v_b  = (const float*)d_in[6];
  const float* o_w  = (const float*)d_in[7];
  const float* o_b  = (const float*)d_in[8];
  float* out = (float*)d_out;

  char* w = (char*)d_ws;
  const size_t XD = (size_t)M_ * D_;
  const size_t WD = (size_t)D_ * D_;
  u16* Xb  = (u16*)(w);                 w += XD * 2;
  u16* Wtq = (u16*)(w);                 w += WD * 2;   // q,k,v,o contiguous
  u16* Wtk = (u16*)(w);                 w += WD * 2;
  u16* Wtv = (u16*)(w);                 w += WD * 2;
  u16* Wto = (u16*)(w);                 w += WD * 2;
  u16* Qb  = (u16*)(w);                 w += XD * 2;   // q,k,v outputs contiguous
  u16* Kb  = (u16*)(w);                 w += XD * 2;
  u16* Vb  = (u16*)(w);                 w += XD * 2;
  u16* Vt  = (u16*)(w);                 w += (size_t)B_ * H_ * HD_ * SPAD * 2;
  u16* Ctx = Xb;   // alias: Xb dead after QKV projection
  (void)Wtk; (void)Wtv;

  k_conv<<<dim3(3750), dim3(256), 0, stream>>>(hs, Xb);
  k_trans4<<<dim3(40, 40, 4), dim3(256), 0, stream>>>(q_w, k_w, v_w, o_w, Wtq);

  k_gemmqkv<<<dim3(47, 30), dim3(256), 0, stream>>>(Xb, Wtq, q_b, v_b, Qb);
  k_vtrans<<<dim3(80, 12), dim3(256), 0, stream>>>(Vb, Vt);

  k_attn<<<dim3(1920), dim3(256), 0, stream>>>(Qb, Kb, Vt, mask, Ctx);

  k_gemmo<<<dim3(47, 10), dim3(256), 0, stream>>>(Ctx, Wto, o_b, out);
}